// Round 5
// baseline (109.849 us; speedup 1.0000x reference)
//
#include <hip/hip_runtime.h>

#define CROP 14
#define NPOS (CROP * CROP)        // 196
#define CHANNELS 256
#define CPB 64                    // channels per chunk
#define NCHUNK (CHANNELS / CPB)   // 4
#define PER_PROP (NPOS * NCHUNK)  // 784 threads of work per proposal

// One thread = one (proposal, chunk, crop-position); loops over 64 channels.
// All bilinear state (4 corner offsets + 4 weights) lives in registers,
// computed once per thread. No LDS, no __syncthreads.
__global__ __launch_bounds__(256) void crop_roi_kernel(
    const float* __restrict__ p2, const float* __restrict__ p3,
    const float* __restrict__ p4, const float* __restrict__ p5,
    const float* __restrict__ props, float* __restrict__ out, int total)
{
    const int J = blockIdx.x * 256 + threadIdx.x;
    if (J >= total) return;

    const int n     = J / PER_PROP;            // proposal (magic mul)
    const int r     = J - n * PER_PROP;
    const int chunk = r / NPOS;                // 0..3
    const int pos   = r - chunk * NPOS;        // 0..195
    const int py    = pos / CROP;
    const int px    = pos - py * CROP;

    // ---- per-thread proposal setup (props is tiny; L2-broadcast reads) ----
    const float bi  = props[n * 7 + 0];
    const float bx0 = props[n * 7 + 1];
    const float by0 = props[n * 7 + 2];
    const float bx1 = props[n * 7 + 3];
    const float by1 = props[n * 7 + 4];

    const float sz = sqrtf((bx1 - bx0) * (by1 - by0));

    // argmin |sz - base|, first-occurrence tie-break (matches jnp.argmin)
    int lvl = 0;
    float bd = fabsf(sz - 8.0f);
    float d;
    d = fabsf(sz - 16.0f); if (d < bd) { bd = d; lvl = 1; }
    d = fabsf(sz - 32.0f); if (d < bd) { bd = d; lvl = 2; }
    d = fabsf(sz - 64.0f); if (d < bd) { bd = d; lvl = 3; }

    const int   H     = 256 >> lvl;                 // H == W per level
    const int   HW    = H * H;
    const float scale = 0.25f / (float)(1 << lvl);  // exact powers of two

    const float* fp = (lvl == 0) ? p2 : (lvl == 1) ? p3 : (lvl == 2) ? p4 : p5;
    const float* base = fp + (size_t)((int)bi) * CHANNELS * HW
                           + (size_t)(chunk * CPB) * HW;

    // y sample (ref op order: scale first, then lerp with g = i/13)
    const float gy  = (float)py / 13.0f;
    const float ys0 = by0 * scale, ys1 = by1 * scale;
    const float ys  = ys0 + (ys1 - ys0) * gy;
    const float yf  = floorf(ys);
    const float ly  = ys - yf;                      // unclamped frac (ref)
    const int   yi0 = min(max((int)yf, 0), H - 1);
    const int   yi1 = min(yi0 + 1, H - 1);

    // x sample
    const float gx  = (float)px / 13.0f;
    const float xs0 = bx0 * scale, xs1 = bx1 * scale;
    const float xs  = xs0 + (xs1 - xs0) * gx;
    const float xf  = floorf(xs);
    const float lx  = xs - xf;
    const int   xi0 = min(max((int)xf, 0), H - 1);
    const int   xi1 = min(xi0 + 1, H - 1);

    const int o00 = yi0 * H + xi0;
    const int o01 = yi0 * H + xi1;
    const int o10 = yi1 * H + xi0;
    const int o11 = yi1 * H + xi1;

    const float omy = 1.0f - ly, omx = 1.0f - lx;
    const float w00 = omy * omx;
    const float w01 = omy * lx;
    const float w10 = ly * omx;
    const float w11 = ly * lx;

    // ---- channel loop: independent iterations, 16 gathers in flight ----
    float* __restrict__ op = out + (size_t)n * (CHANNELS * NPOS)
                                 + (size_t)(chunk * CPB) * NPOS + pos;

    #pragma unroll 4
    for (int c = 0; c < CPB; ++c) {
        const int off = c * HW;
        const float v = base[off + o00] * w00 + base[off + o01] * w01
                      + base[off + o10] * w10 + base[off + o11] * w11;
        op[c * NPOS] = v;   // lanes = consecutive pos -> contiguous stores
    }
}

extern "C" void kernel_launch(void* const* d_in, const int* in_sizes, int n_in,
                              void* d_out, int out_size, void* d_ws, size_t ws_size,
                              hipStream_t stream) {
    const float* p2    = (const float*)d_in[0];
    const float* p3    = (const float*)d_in[1];
    const float* p4    = (const float*)d_in[2];
    const float* p5    = (const float*)d_in[3];
    const float* props = (const float*)d_in[4];
    float* outp        = (float*)d_out;

    const int N     = in_sizes[4] / 7;        // 1024 proposals
    const int total = N * PER_PROP;           // 802816 threads
    dim3 grid((total + 255) / 256);           // 3136 blocks
    dim3 block(256);
    hipLaunchKernelGGL(crop_roi_kernel, grid, block, 0, stream,
                       p2, p3, p4, p5, props, outp, total);
}

// Round 6
// 106.261 us; speedup vs baseline: 1.0338x; 1.0338x over previous
//
#include <hip/hip_runtime.h>

#define CROP 14
#define NPOS (CROP * CROP)        // 196
#define CHANNELS 256
#define CPB 64                    // channels per chunk
#define NCHUNK (CHANNELS / CPB)   // 4
#define PER_PROP (NPOS * NCHUNK)  // 784 threads of work per proposal
#define UNROLL 8                  // channels batched per load group

// One thread = one (proposal, chunk, crop-position); loops over 64 channels
// in batches of 8: 32 independent gathers issued before any use -> deep MLP.
// All bilinear state (4 corner offsets + 4 weights) lives in registers.
__global__ __launch_bounds__(256) void crop_roi_kernel(
    const float* __restrict__ p2, const float* __restrict__ p3,
    const float* __restrict__ p4, const float* __restrict__ p5,
    const float* __restrict__ props, float* __restrict__ out, int total)
{
    const int J = blockIdx.x * 256 + threadIdx.x;
    if (J >= total) return;

    const int n     = J / PER_PROP;            // proposal (magic mul)
    const int r     = J - n * PER_PROP;
    const int chunk = r / NPOS;                // 0..3
    const int pos   = r - chunk * NPOS;        // 0..195
    const int py    = pos / CROP;
    const int px    = pos - py * CROP;

    // ---- per-thread proposal setup (props is tiny; L2-broadcast reads) ----
    const float bi  = props[n * 7 + 0];
    const float bx0 = props[n * 7 + 1];
    const float by0 = props[n * 7 + 2];
    const float bx1 = props[n * 7 + 3];
    const float by1 = props[n * 7 + 4];

    const float sz = sqrtf((bx1 - bx0) * (by1 - by0));

    // argmin |sz - base|, first-occurrence tie-break (matches jnp.argmin)
    int lvl = 0;
    float bd = fabsf(sz - 8.0f);
    float d;
    d = fabsf(sz - 16.0f); if (d < bd) { bd = d; lvl = 1; }
    d = fabsf(sz - 32.0f); if (d < bd) { bd = d; lvl = 2; }
    d = fabsf(sz - 64.0f); if (d < bd) { bd = d; lvl = 3; }

    const int   H     = 256 >> lvl;                 // H == W per level
    const int   HW    = H * H;
    const float scale = 0.25f / (float)(1 << lvl);  // exact powers of two

    const float* fp = (lvl == 0) ? p2 : (lvl == 1) ? p3 : (lvl == 2) ? p4 : p5;
    const float* base = fp + (size_t)((int)bi) * CHANNELS * HW
                           + (size_t)(chunk * CPB) * HW;

    // y sample (ref op order: scale first, then lerp with g = i/13)
    const float gy  = (float)py / 13.0f;
    const float ys0 = by0 * scale, ys1 = by1 * scale;
    const float ys  = ys0 + (ys1 - ys0) * gy;
    const float yf  = floorf(ys);
    const float ly  = ys - yf;                      // unclamped frac (ref)
    const int   yi0 = min(max((int)yf, 0), H - 1);
    const int   yi1 = min(yi0 + 1, H - 1);

    // x sample
    const float gx  = (float)px / 13.0f;
    const float xs0 = bx0 * scale, xs1 = bx1 * scale;
    const float xs  = xs0 + (xs1 - xs0) * gx;
    const float xf  = floorf(xs);
    const float lx  = xs - xf;
    const int   xi0 = min(max((int)xf, 0), H - 1);
    const int   xi1 = min(xi0 + 1, H - 1);

    const int o00 = yi0 * H + xi0;
    const int o01 = yi0 * H + xi1;
    const int o10 = yi1 * H + xi0;
    const int o11 = yi1 * H + xi1;

    const float omy = 1.0f - ly, omx = 1.0f - lx;
    const float w00 = omy * omx;
    const float w01 = omy * lx;
    const float w10 = ly * omx;
    const float w11 = ly * lx;

    float* __restrict__ op = out + (size_t)n * (CHANNELS * NPOS)
                                 + (size_t)(chunk * CPB) * NPOS + pos;

    // ---- channel loop, 8-wide batches: 32 loads in flight per batch ----
    for (int c = 0; c < CPB; c += UNROLL) {
        float v00[UNROLL], v01[UNROLL], v10[UNROLL], v11[UNROLL];

        #pragma unroll
        for (int u = 0; u < UNROLL; ++u) {
            const float* __restrict__ f = base + (size_t)(c + u) * HW;
            v00[u] = f[o00];
            v01[u] = f[o01];
            v10[u] = f[o10];
            v11[u] = f[o11];
        }

        #pragma unroll
        for (int u = 0; u < UNROLL; ++u) {
            const float res = v00[u] * w00 + v01[u] * w01
                            + v10[u] * w10 + v11[u] * w11;
            // lanes = consecutive pos -> contiguous 256B store per instr
            __builtin_nontemporal_store(res, op + (c + u) * NPOS);
        }
    }
}

extern "C" void kernel_launch(void* const* d_in, const int* in_sizes, int n_in,
                              void* d_out, int out_size, void* d_ws, size_t ws_size,
                              hipStream_t stream) {
    const float* p2    = (const float*)d_in[0];
    const float* p3    = (const float*)d_in[1];
    const float* p4    = (const float*)d_in[2];
    const float* p5    = (const float*)d_in[3];
    const float* props = (const float*)d_in[4];
    float* outp        = (float*)d_out;

    const int N     = in_sizes[4] / 7;        // 1024 proposals
    const int total = N * PER_PROP;           // 802816 threads
    dim3 grid((total + 255) / 256);           // 3136 blocks
    dim3 block(256);
    hipLaunchKernelGGL(crop_roi_kernel, grid, block, 0, stream,
                       p2, p3, p4, p5, props, outp, total);
}

// Round 7
// 99.869 us; speedup vs baseline: 1.0999x; 1.0640x over previous
//
#include <hip/hip_runtime.h>

#define CROP 14
#define NPOS (CROP * CROP)        // 196
#define CHANNELS 256
#define CPB 64                    // channels per chunk
#define NCHUNK (CHANNELS / CPB)   // 4
#define PER_PROP (NPOS * NCHUNK)  // 784 threads of work per proposal
#define UNROLL 8                  // channels batched per load group

typedef float __attribute__((ext_vector_type(2))) fx2;

// One thread = one (proposal, chunk, crop-position); loops over 64 channels
// in batches of 8. Per channel: TWO float2 loads (row pairs covering both
// x-corners) instead of four scalar gathers -> half the vmem instructions,
// same cache lines. sched_barrier pins all 16 loads in flight per batch.
__global__ __launch_bounds__(256, 4) void crop_roi_kernel(
    const float* __restrict__ p2, const float* __restrict__ p3,
    const float* __restrict__ p4, const float* __restrict__ p5,
    const float* __restrict__ props, float* __restrict__ out, int total)
{
    const int J = blockIdx.x * 256 + threadIdx.x;
    if (J >= total) return;

    const int n     = J / PER_PROP;            // proposal (magic mul)
    const int r     = J - n * PER_PROP;
    const int chunk = r / NPOS;                // 0..3
    const int pos   = r - chunk * NPOS;        // 0..195
    const int py    = pos / CROP;
    const int px    = pos - py * CROP;

    // ---- per-thread proposal setup (props is tiny; L2-broadcast reads) ----
    const float bi  = props[n * 7 + 0];
    const float bx0 = props[n * 7 + 1];
    const float by0 = props[n * 7 + 2];
    const float bx1 = props[n * 7 + 3];
    const float by1 = props[n * 7 + 4];

    const float sz = sqrtf((bx1 - bx0) * (by1 - by0));

    // argmin |sz - base|, first-occurrence tie-break (matches jnp.argmin)
    int lvl = 0;
    float bd = fabsf(sz - 8.0f);
    float d;
    d = fabsf(sz - 16.0f); if (d < bd) { bd = d; lvl = 1; }
    d = fabsf(sz - 32.0f); if (d < bd) { bd = d; lvl = 2; }
    d = fabsf(sz - 64.0f); if (d < bd) { bd = d; lvl = 3; }

    const int   H     = 256 >> lvl;                 // H == W per level
    const int   HW    = H * H;
    const float scale = 0.25f / (float)(1 << lvl);  // exact powers of two

    const float* fp = (lvl == 0) ? p2 : (lvl == 1) ? p3 : (lvl == 2) ? p4 : p5;
    const float* base = fp + (size_t)((int)bi) * CHANNELS * HW
                           + (size_t)(chunk * CPB) * HW;

    // y sample (ref op order: scale first, then lerp with g = i/13)
    const float gy  = (float)py / 13.0f;
    const float ys0 = by0 * scale, ys1 = by1 * scale;
    const float ys  = ys0 + (ys1 - ys0) * gy;
    const float yf  = floorf(ys);
    const float ly  = ys - yf;                      // unclamped frac (ref)
    const int   yi0 = min(max((int)yf, 0), H - 1);

    // x sample
    const float gx  = (float)px / 13.0f;
    const float xs0 = bx0 * scale, xs1 = bx1 * scale;
    const float xs  = xs0 + (xs1 - xs0) * gx;
    const float xf  = floorf(xs);
    const float lx  = xs - xf;
    const int   xi0 = min(max((int)xf, 0), H - 1);

    // Shifted-base + adjusted-weight formulation:
    //   interior: load float2 at xi0 -> (g[xi0], g[xi0+1]), weights (1-lx, lx)
    //   high clamp (xi0==H-1): ref value collapses to g[H-1]; load float2 at
    //   H-2 -> (g[H-2], g[H-1]), weights (0, 1). Same for y (row pair).
    const bool xcl = (xi0 == H - 1);
    const int  bx  = xcl ? H - 2 : xi0;
    const float wx0 = xcl ? 0.0f : (1.0f - lx);
    const float wx1 = xcl ? 1.0f : lx;

    const bool ycl = (yi0 == H - 1);
    const int  by  = ycl ? H - 2 : yi0;
    const float wy0 = ycl ? 0.0f : (1.0f - ly);
    const float wy1 = ycl ? 1.0f : ly;

    const int r0 = by * H + bx;     // row 0 pair offset (floats)
    const int r1 = r0 + H;          // row 1 pair offset

    float* __restrict__ op = out + (size_t)n * (CHANNELS * NPOS)
                                 + (size_t)(chunk * CPB) * NPOS + pos;

    // ---- channel loop, 8-wide batches: 16 dwordx2 loads in flight ----
    for (int c = 0; c < CPB; c += UNROLL) {
        fx2 A[UNROLL], B[UNROLL];

        #pragma unroll
        for (int u = 0; u < UNROLL; ++u) {
            const float* __restrict__ f = base + (size_t)(c + u) * HW;
            A[u] = *reinterpret_cast<const fx2*>(f + r0);
            B[u] = *reinterpret_cast<const fx2*>(f + r1);
        }

        // Pin the 16 loads before any consumer (defeat min-reg rescheduling)
        __builtin_amdgcn_sched_barrier(0);

        #pragma unroll
        for (int u = 0; u < UNROLL; ++u) {
            const float row0 = A[u].x * wx0 + A[u].y * wx1;
            const float row1 = B[u].x * wx0 + B[u].y * wx1;
            // lanes = consecutive pos -> contiguous 256B store per instr
            op[(c + u) * NPOS] = row0 * wy0 + row1 * wy1;
        }
    }
}

extern "C" void kernel_launch(void* const* d_in, const int* in_sizes, int n_in,
                              void* d_out, int out_size, void* d_ws, size_t ws_size,
                              hipStream_t stream) {
    const float* p2    = (const float*)d_in[0];
    const float* p3    = (const float*)d_in[1];
    const float* p4    = (const float*)d_in[2];
    const float* p5    = (const float*)d_in[3];
    const float* props = (const float*)d_in[4];
    float* outp        = (float*)d_out;

    const int N     = in_sizes[4] / 7;        // 1024 proposals
    const int total = N * PER_PROP;           // 802816 threads
    dim3 grid((total + 255) / 256);           // 3136 blocks
    dim3 block(256);
    hipLaunchKernelGGL(crop_roi_kernel, grid, block, 0, stream,
                       p2, p3, p4, p5, props, outp, total);
}

// Round 8
// 85.443 us; speedup vs baseline: 1.2856x; 1.1688x over previous
//
#include <hip/hip_runtime.h>

#define CROP 14
#define NPOS (CROP * CROP)       // 196
#define CHANNELS 256
#define CPB 64                   // channels per block
#define LDS_FLOATS 10240         // 40 KiB window buffer -> 4 blocks/CU

// Block = (proposal, 64-channel chunk). Stage the ROI's bilinear source
// window for a group of channels into LDS (coalesced), then each thread
// (one fixed crop position) samples 4 LDS floats per channel.
__global__ __launch_bounds__(256) void crop_roi_kernel(
    const float* __restrict__ p2, const float* __restrict__ p3,
    const float* __restrict__ p4, const float* __restrict__ p5,
    const float* __restrict__ props, float* __restrict__ out)
{
    const int blk   = blockIdx.x;
    const int n     = blk >> 2;            // proposal
    const int chunk = blk & 3;             // 64-channel chunk
    const int tid   = threadIdx.x;
    const int lane  = tid & 63;
    const int wid   = tid >> 6;

    __shared__ float win[LDS_FLOATS];

    // ---- proposal setup (uniform across block; computed redundantly) ----
    const int   bimg = (int)props[n * 7 + 0];
    const float bx0  = props[n * 7 + 1];
    const float by0  = props[n * 7 + 2];
    const float bx1  = props[n * 7 + 3];
    const float by1  = props[n * 7 + 4];

    const float sz = sqrtf((bx1 - bx0) * (by1 - by0));
    int lvl = 0; float bd = fabsf(sz - 8.0f), d;
    d = fabsf(sz - 16.0f); if (d < bd) { bd = d; lvl = 1; }
    d = fabsf(sz - 32.0f); if (d < bd) { bd = d; lvl = 2; }
    d = fabsf(sz - 64.0f); if (d < bd) { bd = d; lvl = 3; }

    const int   H     = 256 >> lvl;                 // H == W
    const int   HW    = H * H;
    const float scale = 0.25f / (float)(1 << lvl);  // exact
    const float* fp   = (lvl == 0) ? p2 : (lvl == 1) ? p3 : (lvl == 2) ? p4 : p5;
    const float* base = fp + (size_t)bimg * CHANNELS * HW
                           + (size_t)(chunk * CPB) * HW;

    // ---- window bounds (uniform). Samples use shifted-base clamping:
    // bx = min(xi0, H-2), so columns lie in [x_lo, x_hi], rows in [y_lo, y_hi].
    const float xs0 = bx0 * scale, xs1 = bx1 * scale;
    const float ys0 = by0 * scale, ys1 = by1 * scale;
    const int x_lo = min((int)floorf(xs0), H - 2);
    const int x_hi = min((int)floorf(xs1), H - 2) + 1;
    const int y_lo = min((int)floorf(ys0), H - 2);
    const int y_hi = min((int)floorf(ys1), H - 2) + 1;
    const int WW = x_hi - x_lo + 1;        // 2..32
    const int WH = y_hi - y_lo + 1;        // 2..32

    const int lw   = 32 - __clz(WW - 1);   // row stride = 2^lw >= WW
    const int ww   = 1 << lw;
    const int SLOT = WH << lw;             // floats per channel slot (<=1024)
    int CG = LDS_FLOATS / SLOT; if (CG > CPB) CG = CPB;

    // ---- staging lane geometry ----
    const int  wxl = lane & (ww - 1);
    const int  wyo = lane >> lw;
    const int  kR  = 64 >> lw;             // rows per wave pass (>=2)
    const bool wok = (wxl < WW);

    // ---- per-thread sample registers (pos fixed; only tid<196 computes) ----
    const int pos = tid;
    const int py  = pos / CROP;
    const int px  = pos - py * CROP;

    const float gy  = (float)py / 13.0f;
    const float ysv = ys0 + (ys1 - ys0) * gy;
    const float yfv = floorf(ysv);
    const float ly  = ysv - yfv;                    // unclamped frac (ref)
    const int   yi0 = min((int)yfv, H - 1);         // ysv >= 0 always
    const bool  ycl = (yi0 == H - 1);
    const int   byl = (ycl ? H - 2 : yi0) - y_lo;   // local row
    const float wy0 = ycl ? 0.0f : 1.0f - ly;
    const float wy1 = ycl ? 1.0f : ly;

    const float gx  = (float)px / 13.0f;
    const float xsv = xs0 + (xs1 - xs0) * gx;
    const float xfv = floorf(xsv);
    const float lx  = xsv - xfv;
    const int   xi0 = min((int)xfv, H - 1);
    const bool  xcl = (xi0 == H - 1);
    const int   bxl = (xcl ? H - 2 : xi0) - x_lo;   // local col
    const float wx0 = xcl ? 0.0f : 1.0f - lx;
    const float wx1 = xcl ? 1.0f : lx;

    float* __restrict__ op = out + ((size_t)n * CHANNELS + chunk * CPB) * NPOS + pos;

    // ---- group loop: stage CG channel windows, then sample them ----
    for (int g0 = 0; g0 < CPB; g0 += CG) {
        const int gn = min(CG, CPB - g0);
        if (g0) __syncthreads();           // protect previous group's reads

        // stage: wave w handles channels w, w+4, ... (coalesced row loads)
        for (int c = wid; c < gn; c += 4) {
            const float* __restrict__ f = base + (size_t)(g0 + c) * HW
                                               + (size_t)y_lo * H + x_lo;
            float* __restrict__ w = &win[(c * WH) << lw];
            if (wok) {
                for (int wy = wyo; wy < WH; wy += kR)
                    w[(wy << lw) + wxl] = f[wy * H + wxl];
            }
        }
        __syncthreads();

        if (tid < NPOS) {
            int a = (byl << lw) + bxl;     // dword index in slot 0
            for (int c = 0; c < gn; ++c) {
                const float v00 = win[a];
                const float v01 = win[a + 1];        // ds_read2_b32 pair
                const float v10 = win[a + ww];
                const float v11 = win[a + ww + 1];   // ds_read2_b32 pair
                const float r0 = v00 * wx0 + v01 * wx1;
                const float r1 = v10 * wx0 + v11 * wx1;
                op[(size_t)(g0 + c) * NPOS] = r0 * wy0 + r1 * wy1;
                a += SLOT;
            }
        }
    }
}

extern "C" void kernel_launch(void* const* d_in, const int* in_sizes, int n_in,
                              void* d_out, int out_size, void* d_ws, size_t ws_size,
                              hipStream_t stream) {
    const float* p2    = (const float*)d_in[0];
    const float* p3    = (const float*)d_in[1];
    const float* p4    = (const float*)d_in[2];
    const float* p5    = (const float*)d_in[3];
    const float* props = (const float*)d_in[4];
    float* outp        = (float*)d_out;

    const int N = in_sizes[4] / 7;          // 1024 proposals
    dim3 grid(N * 4);                       // 4096 blocks
    dim3 block(256);
    hipLaunchKernelGGL(crop_roi_kernel, grid, block, 0, stream,
                       p2, p3, p4, p5, props, outp);
}

// Round 9
// 77.996 us; speedup vs baseline: 1.4084x; 1.0955x over previous
//
#include <hip/hip_runtime.h>

#define CROP 14
#define NPOS (CROP * CROP)       // 196
#define CHANNELS 256
#define CPB 64                   // channels per block
#define LDS_FLOATS 5056          // ~19.8 KiB -> 8 blocks/CU (100% waves)

// Block = (proposal, 64-channel chunk). Stage the ROI's bilinear source
// window (exact-WW row stride, no pow2 padding) for a group of channels
// into LDS (coalesced), then each thread (one fixed crop position)
// samples 4 LDS floats per channel.
__global__ __launch_bounds__(256) void crop_roi_kernel(
    const float* __restrict__ p2, const float* __restrict__ p3,
    const float* __restrict__ p4, const float* __restrict__ p5,
    const float* __restrict__ props, float* __restrict__ out)
{
    const int blk   = blockIdx.x;
    const int n     = blk >> 2;            // proposal
    const int chunk = blk & 3;             // 64-channel chunk
    const int tid   = threadIdx.x;
    const int lane  = tid & 63;
    const int wid   = tid >> 6;

    __shared__ float win[LDS_FLOATS];

    // ---- proposal setup (uniform across block; computed redundantly) ----
    const int   bimg = (int)props[n * 7 + 0];
    const float bx0  = props[n * 7 + 1];
    const float by0  = props[n * 7 + 2];
    const float bx1  = props[n * 7 + 3];
    const float by1  = props[n * 7 + 4];

    const float sz = sqrtf((bx1 - bx0) * (by1 - by0));
    int lvl = 0; float bd = fabsf(sz - 8.0f), d;
    d = fabsf(sz - 16.0f); if (d < bd) { bd = d; lvl = 1; }
    d = fabsf(sz - 32.0f); if (d < bd) { bd = d; lvl = 2; }
    d = fabsf(sz - 64.0f); if (d < bd) { bd = d; lvl = 3; }

    const int   H     = 256 >> lvl;                 // H == W
    const int   HW    = H * H;
    const float scale = 0.25f / (float)(1 << lvl);  // exact
    const float* fp   = (lvl == 0) ? p2 : (lvl == 1) ? p3 : (lvl == 2) ? p4 : p5;
    const float* base = fp + (size_t)bimg * CHANNELS * HW
                           + (size_t)(chunk * CPB) * HW;

    // ---- window bounds (uniform). Samples use shifted-base clamping:
    // col = min(xi0, H-2) in [x_lo, x_hi-1], so window cols [x_lo, x_hi].
    const float xs0 = bx0 * scale, xs1 = bx1 * scale;
    const float ys0 = by0 * scale, ys1 = by1 * scale;
    const int x_lo = min((int)floorf(xs0), H - 2);
    const int x_hi = min((int)floorf(xs1), H - 2) + 1;
    const int y_lo = min((int)floorf(ys0), H - 2);
    const int y_hi = min((int)floorf(ys1), H - 2) + 1;
    const int WW = x_hi - x_lo + 1;        // 2..~28
    const int WH = y_hi - y_lo + 1;        // 2..~28
    const int SLOT = WH * WW;              // floats per channel slot

    int CG = LDS_FLOATS / SLOT; if (CG > CPB) CG = CPB;

    // ---- staging lane geometry (one-time runtime div/mod) ----
    const int  wyo = lane / WW;            // row within pass
    const int  wxl = lane - wyo * WW;      // col
    const int  kR  = 64 / WW;              // complete rows per wave pass
    const bool wok = (lane < kR * WW);     // drop partial tail row

    // ---- per-thread sample registers (pos fixed; only tid<196 computes) ----
    const int pos = tid;
    const int py  = pos / CROP;
    const int px  = pos - py * CROP;

    const float gy  = (float)py / 13.0f;
    const float ysv = ys0 + (ys1 - ys0) * gy;
    const float yfv = floorf(ysv);
    const float ly  = ysv - yfv;                    // unclamped frac (ref)
    const int   yi0 = min((int)yfv, H - 1);         // ysv >= 0 always
    const bool  ycl = (yi0 == H - 1);
    const int   byl = (ycl ? H - 2 : yi0) - y_lo;   // local row
    const float wy0 = ycl ? 0.0f : 1.0f - ly;
    const float wy1 = ycl ? 1.0f : ly;

    const float gx  = (float)px / 13.0f;
    const float xsv = xs0 + (xs1 - xs0) * gx;
    const float xfv = floorf(xsv);
    const float lx  = xsv - xfv;
    const int   xi0 = min((int)xfv, H - 1);
    const bool  xcl = (xi0 == H - 1);
    const int   bxl = (xcl ? H - 2 : xi0) - x_lo;   // local col
    const float wx0 = xcl ? 0.0f : 1.0f - lx;
    const float wx1 = xcl ? 1.0f : lx;

    const int a0 = byl * WW + bxl;         // sample index inside a slot

    float* __restrict__ op = out + ((size_t)n * CHANNELS + chunk * CPB) * NPOS + pos;

    // ---- group loop: stage CG channel windows, then sample them ----
    for (int g0 = 0; g0 < CPB; g0 += CG) {
        const int gn = min(CG, CPB - g0);
        if (g0) __syncthreads();           // protect previous group's reads

        // stage: wave w handles channels w, w+4, ... (coalesced row loads)
        if (wok) {
            for (int c = wid; c < gn; c += 4) {
                const float* __restrict__ f = base + (size_t)(g0 + c) * HW
                                                   + (size_t)y_lo * H + x_lo;
                float* __restrict__ w = &win[c * SLOT];
                for (int wy = wyo; wy < WH; wy += kR)
                    w[wy * WW + wxl] = f[wy * H + wxl];
            }
        }
        __syncthreads();

        if (tid < NPOS) {
            int a = a0;
            #pragma unroll 2
            for (int c = 0; c < gn; ++c) {
                const float v00 = win[a];
                const float v01 = win[a + 1];         // ds_read2_b32 pair
                const float v10 = win[a + WW];
                const float v11 = win[a + WW + 1];    // ds_read2_b32 pair
                const float r0 = v00 * wx0 + v01 * wx1;
                const float r1 = v10 * wx0 + v11 * wx1;
                op[(size_t)(g0 + c) * NPOS] = r0 * wy0 + r1 * wy1;
                a += SLOT;
            }
        }
    }
}

extern "C" void kernel_launch(void* const* d_in, const int* in_sizes, int n_in,
                              void* d_out, int out_size, void* d_ws, size_t ws_size,
                              hipStream_t stream) {
    const float* p2    = (const float*)d_in[0];
    const float* p3    = (const float*)d_in[1];
    const float* p4    = (const float*)d_in[2];
    const float* p5    = (const float*)d_in[3];
    const float* props = (const float*)d_in[4];
    float* outp        = (float*)d_out;

    const int N = in_sizes[4] / 7;          // 1024 proposals
    dim3 grid(N * 4);                       // 4096 blocks
    dim3 block(256);
    hipLaunchKernelGGL(crop_roi_kernel, grid, block, 0, stream,
                       p2, p3, p4, p5, props, outp);
}

// Round 10
// 76.713 us; speedup vs baseline: 1.4319x; 1.0167x over previous
//
#include <hip/hip_runtime.h>

#define CROP 14
#define NPOS (CROP * CROP)       // 196
#define CHANNELS 256
#define CPB 64                   // channels per block
#define LDS_FLOATS 5056          // ~19.8 KiB
#define SLOT_MAX 392             // stage only if texel reuse >= 2x (784/SLOT)

// Block = (proposal, 64-channel chunk).
// Small windows (SLOT<=392): stage window in LDS, sample from LDS.
// Large windows: direct register gather (reuse ~1x -> staging is pure overhead).
__global__ __launch_bounds__(256) void crop_roi_kernel(
    const float* __restrict__ p2, const float* __restrict__ p3,
    const float* __restrict__ p4, const float* __restrict__ p5,
    const float* __restrict__ props, float* __restrict__ out)
{
    const int blk   = blockIdx.x;
    const int n     = blk >> 2;            // proposal
    const int chunk = blk & 3;             // 64-channel chunk
    const int tid   = threadIdx.x;
    const int lane  = tid & 63;
    const int wid   = tid >> 6;

    __shared__ float win[LDS_FLOATS];

    // ---- proposal setup (uniform across block; computed redundantly) ----
    const int   bimg = (int)props[n * 7 + 0];
    const float bx0  = props[n * 7 + 1];
    const float by0  = props[n * 7 + 2];
    const float bx1  = props[n * 7 + 3];
    const float by1  = props[n * 7 + 4];

    const float sz = sqrtf((bx1 - bx0) * (by1 - by0));
    int lvl = 0; float bd = fabsf(sz - 8.0f), d;
    d = fabsf(sz - 16.0f); if (d < bd) { bd = d; lvl = 1; }
    d = fabsf(sz - 32.0f); if (d < bd) { bd = d; lvl = 2; }
    d = fabsf(sz - 64.0f); if (d < bd) { bd = d; lvl = 3; }

    const int   H     = 256 >> lvl;                 // H == W
    const int   HW    = H * H;
    const float scale = 0.25f / (float)(1 << lvl);  // exact
    const float* fp   = (lvl == 0) ? p2 : (lvl == 1) ? p3 : (lvl == 2) ? p4 : p5;
    const float* base = fp + (size_t)bimg * CHANNELS * HW
                           + (size_t)(chunk * CPB) * HW;

    // ---- window bounds (uniform) ----
    const float xs0 = bx0 * scale, xs1 = bx1 * scale;
    const float ys0 = by0 * scale, ys1 = by1 * scale;
    const int x_lo = min((int)floorf(xs0), H - 2);
    const int x_hi = min((int)floorf(xs1), H - 2) + 1;
    const int y_lo = min((int)floorf(ys0), H - 2);
    const int y_hi = min((int)floorf(ys1), H - 2) + 1;
    const int WW = x_hi - x_lo + 1;
    const int WH = y_hi - y_lo + 1;
    const int SLOT = WH * WW;              // floats per channel window

    // ---- per-thread sample coords (pos fixed; tid<196) ----
    const int pos = tid;
    const int py  = pos / CROP;
    const int px  = pos - py * CROP;

    const float gy  = (float)py / 13.0f;
    const float ysv = ys0 + (ys1 - ys0) * gy;
    const float yfv = floorf(ysv);
    const float ly  = ysv - yfv;                    // unclamped frac (ref)
    const int   yi0 = min((int)yfv, H - 1);         // ysv >= 0 always
    const bool  ycl = (yi0 == H - 1);

    const float gx  = (float)px / 13.0f;
    const float xsv = xs0 + (xs1 - xs0) * gx;
    const float xfv = floorf(xsv);
    const float lx  = xsv - xfv;
    const int   xi0 = min((int)xfv, H - 1);
    const bool  xcl = (xi0 == H - 1);

    float* __restrict__ op = out + ((size_t)n * CHANNELS + chunk * CPB) * NPOS + pos;

    if (SLOT <= SLOT_MAX) {
        // ================= staged path (texel reuse >= 2x) =================
        // shifted-base + adjusted-weight clamping
        const int   byl = (ycl ? H - 2 : yi0) - y_lo;
        const float wy0 = ycl ? 0.0f : 1.0f - ly;
        const float wy1 = ycl ? 1.0f : ly;
        const int   bxl = (xcl ? H - 2 : xi0) - x_lo;
        const float wx0 = xcl ? 0.0f : 1.0f - lx;
        const float wx1 = xcl ? 1.0f : lx;
        const int   a0  = byl * WW + bxl;

        int CG = LDS_FLOATS / SLOT; if (CG > CPB) CG = CPB;

        // staging lane geometry
        const int  wyo = lane / WW;
        const int  wxl = lane - wyo * WW;
        const int  kR  = 64 / WW;
        const bool wok = (lane < kR * WW);

        for (int g0 = 0; g0 < CPB; g0 += CG) {
            const int gn = min(CG, CPB - g0);
            if (g0) __syncthreads();

            if (wok) {
                for (int c = wid; c < gn; c += 4) {
                    const float* __restrict__ f = base + (size_t)(g0 + c) * HW
                                                       + (size_t)y_lo * H + x_lo;
                    float* __restrict__ w = &win[c * SLOT];
                    for (int wy = wyo; wy < WH; wy += kR)
                        w[wy * WW + wxl] = f[wy * H + wxl];
                }
            }
            __syncthreads();

            if (tid < NPOS) {
                int a = a0;
                #pragma unroll 2
                for (int c = 0; c < gn; ++c) {
                    const float v00 = win[a];
                    const float v01 = win[a + 1];
                    const float v10 = win[a + WW];
                    const float v11 = win[a + WW + 1];
                    const float r0 = v00 * wx0 + v01 * wx1;
                    const float r1 = v10 * wx0 + v11 * wx1;
                    op[(size_t)(g0 + c) * NPOS] = r0 * wy0 + r1 * wy1;
                    a += SLOT;
                }
            }
        }
    } else {
        // ================= direct path (reuse ~1x; no LDS, no barriers) ====
        if (tid < NPOS) {
            const int yi1 = min(yi0 + 1, H - 1);
            const int xi1 = min(xi0 + 1, H - 1);
            const int o00 = yi0 * H + xi0;
            const int o01 = yi0 * H + xi1;
            const int o10 = yi1 * H + xi0;
            const int o11 = yi1 * H + xi1;
            const float omy = 1.0f - ly, omx = 1.0f - lx;
            const float w00 = omy * omx;
            const float w01 = omy * lx;
            const float w10 = ly * omx;
            const float w11 = ly * lx;

            #pragma unroll 4
            for (int c = 0; c < CPB; ++c) {
                const float* __restrict__ f = base + (size_t)c * HW;
                const float v = f[o00] * w00 + f[o01] * w01
                              + f[o10] * w10 + f[o11] * w11;
                op[(size_t)c * NPOS] = v;
            }
        }
    }
}

extern "C" void kernel_launch(void* const* d_in, const int* in_sizes, int n_in,
                              void* d_out, int out_size, void* d_ws, size_t ws_size,
                              hipStream_t stream) {
    const float* p2    = (const float*)d_in[0];
    const float* p3    = (const float*)d_in[1];
    const float* p4    = (const float*)d_in[2];
    const float* p5    = (const float*)d_in[3];
    const float* props = (const float*)d_in[4];
    float* outp        = (float*)d_out;

    const int N = in_sizes[4] / 7;          // 1024 proposals
    dim3 grid(N * 4);                       // 4096 blocks
    dim3 block(256);
    hipLaunchKernelGGL(crop_roi_kernel, grid, block, 0, stream,
                       p2, p3, p4, p5, props, outp);
}

// Round 11
// 71.140 us; speedup vs baseline: 1.5441x; 1.0783x over previous
//
#include <hip/hip_runtime.h>

#define CROP 14
#define NPOS (CROP * CROP)       // 196
#define CHANNELS 256
#define CPB 64                   // channels per block
#define LDS_HALF 2496            // floats per ping-pong half (2*2496*4 = 19968 B -> 8 blocks/CU)
#define SLOT_MAX 392             // fallback threshold (window too big to stage)

// Block = (proposal, 64-channel chunk).
// Stage ROI windows for a group of channels into LDS via async
// global_load_lds (lane-linear dest), double-buffered so group g+1's
// staging overlaps group g's sampling. One __syncthreads per group.
__global__ __launch_bounds__(256) void crop_roi_kernel(
    const float* __restrict__ p2, const float* __restrict__ p3,
    const float* __restrict__ p4, const float* __restrict__ p5,
    const float* __restrict__ props, float* __restrict__ out)
{
    const int blk   = blockIdx.x;
    const int n     = blk >> 2;            // proposal
    const int chunk = blk & 3;             // 64-channel chunk
    const int tid   = threadIdx.x;
    const int lane  = tid & 63;
    const int wid   = tid >> 6;

    __shared__ float win[2][LDS_HALF];

    // ---- proposal setup (uniform across block; computed redundantly) ----
    const int   bimg = (int)props[n * 7 + 0];
    const float bx0  = props[n * 7 + 1];
    const float by0  = props[n * 7 + 2];
    const float bx1  = props[n * 7 + 3];
    const float by1  = props[n * 7 + 4];

    const float sz = sqrtf((bx1 - bx0) * (by1 - by0));
    int lvl = 0; float bd = fabsf(sz - 8.0f), d;
    d = fabsf(sz - 16.0f); if (d < bd) { bd = d; lvl = 1; }
    d = fabsf(sz - 32.0f); if (d < bd) { bd = d; lvl = 2; }
    d = fabsf(sz - 64.0f); if (d < bd) { bd = d; lvl = 3; }

    const int   H     = 256 >> lvl;                 // H == W
    const int   HW    = H * H;
    const float scale = 0.25f / (float)(1 << lvl);  // exact
    const float* fp   = (lvl == 0) ? p2 : (lvl == 1) ? p3 : (lvl == 2) ? p4 : p5;
    const float* base = fp + (size_t)bimg * CHANNELS * HW
                           + (size_t)(chunk * CPB) * HW;

    // ---- window bounds (uniform) ----
    const float xs0 = bx0 * scale, xs1 = bx1 * scale;
    const float ys0 = by0 * scale, ys1 = by1 * scale;
    const int x_lo = min((int)floorf(xs0), H - 2);
    const int x_hi = min((int)floorf(xs1), H - 2) + 1;
    const int y_lo = min((int)floorf(ys0), H - 2);
    const int y_hi = min((int)floorf(ys1), H - 2) + 1;
    const int WW = x_hi - x_lo + 1;
    const int WH = y_hi - y_lo + 1;
    const int SLOT = WH * WW;              // floats per channel window

    // ---- per-thread sample coords (pos fixed; tid<196) ----
    const int pos = tid;
    const int py  = pos / CROP;
    const int px  = pos - py * CROP;

    const float gy  = (float)py / 13.0f;
    const float ysv = ys0 + (ys1 - ys0) * gy;
    const float yfv = floorf(ysv);
    const float ly  = ysv - yfv;                    // unclamped frac (ref)
    const int   yi0 = min((int)yfv, H - 1);         // ysv >= 0 always
    const bool  ycl = (yi0 == H - 1);

    const float gx  = (float)px / 13.0f;
    const float xsv = xs0 + (xs1 - xs0) * gx;
    const float xfv = floorf(xsv);
    const float lx  = xsv - xfv;
    const int   xi0 = min((int)xfv, H - 1);
    const bool  xcl = (xi0 == H - 1);

    float* __restrict__ op = out + ((size_t)n * CHANNELS + chunk * CPB) * NPOS + pos;

    if (SLOT <= SLOT_MAX) {
        // ================= staged path =================
        // shifted-base + adjusted-weight clamping
        const int   byl = (ycl ? H - 2 : yi0) - y_lo;
        const float wy0 = ycl ? 0.0f : 1.0f - ly;
        const float wy1 = ycl ? 1.0f : ly;
        const int   bxl = (xcl ? H - 2 : xi0) - x_lo;
        const float wx0 = xcl ? 0.0f : 1.0f - lx;
        const float wx1 = xcl ? 1.0f : lx;
        const int   a0  = byl * WW + bxl;

        int CG = LDS_HALF / SLOT; if (CG > CPB) CG = CPB;

        // staging lane geometry: lane l covers (row l/WW, col l%WW) of each
        // kR-row pass; LDS dest element = c*SLOT + p*kR*WW + l (lane-linear,
        // matching global_load_lds' uniform-base + lane*4 write pattern).
        const int  wyo  = lane / WW;
        const int  wxl  = lane - wyo * WW;
        const int  kR   = 64 / WW;           // full rows per pass
        const int  kRWW = kR * WW;
        const bool wok  = (lane < kRWW);

        // async stage: channels [g0, g0+gn) -> win[buf]
        auto stage = [&](int g0, int gn, int buf) {
            for (int c = wid; c < gn; c += 4) {
                const float* __restrict__ f = base + (size_t)(g0 + c) * HW
                                                   + (size_t)y_lo * H + x_lo;
                for (int p = 0; p * kR < WH; ++p) {
                    const int row = p * kR + wyo;
                    if (wok && row < WH) {
                        __builtin_amdgcn_global_load_lds(
                            (const __attribute__((address_space(1))) void*)(f + row * H + wxl),
                            (__attribute__((address_space(3))) void*)&win[buf][c * SLOT + p * kRWW],
                            4, 0, 0);
                    }
                }
            }
        };

        stage(0, min(CG, CPB), 0);

        int gi = 0;
        for (int g0 = 0; g0 < CPB; g0 += CG, ++gi) {
            const int gn = min(CG, CPB - g0);
            // vmcnt(0)+barrier: current buffer's loads arrived; previous
            // group's sampling (which read the other buffer) is finished.
            __syncthreads();

            const int nx = g0 + CG;
            if (nx < CPB) stage(nx, min(CG, CPB - nx), (gi + 1) & 1);

            if (tid < NPOS) {
                const float* __restrict__ w = win[gi & 1];
                int a = a0;
                #pragma unroll 2
                for (int c = 0; c < gn; ++c) {
                    const float v00 = w[a];
                    const float v01 = w[a + 1];
                    const float v10 = w[a + WW];
                    const float v11 = w[a + WW + 1];
                    const float r0 = v00 * wx0 + v01 * wx1;
                    const float r1 = v10 * wx0 + v11 * wx1;
                    op[(size_t)(g0 + c) * NPOS] = r0 * wy0 + r1 * wy1;
                    a += SLOT;
                }
            }
        }
    } else {
        // ================= direct fallback (rare huge windows) =============
        if (tid < NPOS) {
            const int yi1 = min(yi0 + 1, H - 1);
            const int xi1 = min(xi0 + 1, H - 1);
            const int o00 = yi0 * H + xi0;
            const int o01 = yi0 * H + xi1;
            const int o10 = yi1 * H + xi0;
            const int o11 = yi1 * H + xi1;
            const float omy = 1.0f - ly, omx = 1.0f - lx;
            const float w00 = omy * omx;
            const float w01 = omy * lx;
            const float w10 = ly * omx;
            const float w11 = ly * lx;

            #pragma unroll 4
            for (int c = 0; c < CPB; ++c) {
                const float* __restrict__ f = base + (size_t)c * HW;
                const float v = f[o00] * w00 + f[o01] * w01
                              + f[o10] * w10 + f[o11] * w11;
                op[(size_t)c * NPOS] = v;
            }
        }
    }
}

extern "C" void kernel_launch(void* const* d_in, const int* in_sizes, int n_in,
                              void* d_out, int out_size, void* d_ws, size_t ws_size,
                              hipStream_t stream) {
    const float* p2    = (const float*)d_in[0];
    const float* p3    = (const float*)d_in[1];
    const float* p4    = (const float*)d_in[2];
    const float* p5    = (const float*)d_in[3];
    const float* props = (const float*)d_in[4];
    float* outp        = (float*)d_out;

    const int N = in_sizes[4] / 7;          // 1024 proposals
    dim3 grid(N * 4);                       // 4096 blocks
    dim3 block(256);
    hipLaunchKernelGGL(crop_roi_kernel, grid, block, 0, stream,
                       p2, p3, p4, p5, props, outp);
}

// Round 12
// 68.512 us; speedup vs baseline: 1.6033x; 1.0384x over previous
//
#include <hip/hip_runtime.h>

#define CROP 14
#define NPOS (CROP * CROP)       // 196
#define CHANNELS 256
#define CPB 64                   // channels per block
#define LDS_HALF 2496            // 2*2496*4 = 19968 B -> 8 blocks/CU
#define SLOT_MAX 392             // fallback threshold (never fires; safety)
#define NQUAD 49                 // 4-position quads per channel
#define NSUB 5                   // channels sampled concurrently (5*49=245)

typedef float __attribute__((ext_vector_type(4))) fx4;

// Block = (proposal, 64-channel chunk).
// Stage: async global_load_lds, double-buffered (one barrier per group).
// Sample: thread owns a fixed QUAD of 4 crop positions x 1-of-5 channel
// substream -> 8 ds_read2 + 16 FMA + one dwordx4 store per channel.
__global__ __launch_bounds__(256) void crop_roi_kernel(
    const float* __restrict__ p2, const float* __restrict__ p3,
    const float* __restrict__ p4, const float* __restrict__ p5,
    const float* __restrict__ props, float* __restrict__ out)
{
    const int blk   = blockIdx.x;
    const int n     = blk >> 2;            // proposal
    const int chunk = blk & 3;             // 64-channel chunk
    const int tid   = threadIdx.x;
    const int lane  = tid & 63;
    const int wid   = tid >> 6;

    __shared__ float win[2][LDS_HALF];

    // ---- proposal setup (uniform across block; computed redundantly) ----
    const int   bimg = (int)props[n * 7 + 0];
    const float bx0  = props[n * 7 + 1];
    const float by0  = props[n * 7 + 2];
    const float bx1  = props[n * 7 + 3];
    const float by1  = props[n * 7 + 4];

    const float sz = sqrtf((bx1 - bx0) * (by1 - by0));
    int lvl = 0; float bd = fabsf(sz - 8.0f), d;
    d = fabsf(sz - 16.0f); if (d < bd) { bd = d; lvl = 1; }
    d = fabsf(sz - 32.0f); if (d < bd) { bd = d; lvl = 2; }
    d = fabsf(sz - 64.0f); if (d < bd) { bd = d; lvl = 3; }

    const int   H     = 256 >> lvl;                 // H == W
    const int   HW    = H * H;
    const float scale = 0.25f / (float)(1 << lvl);  // exact
    const float* fp   = (lvl == 0) ? p2 : (lvl == 1) ? p3 : (lvl == 2) ? p4 : p5;
    const float* base = fp + (size_t)bimg * CHANNELS * HW
                           + (size_t)(chunk * CPB) * HW;

    // ---- window bounds (uniform) ----
    const float xs0 = bx0 * scale, xs1 = bx1 * scale;
    const float ys0 = by0 * scale, ys1 = by1 * scale;
    const int x_lo = min((int)floorf(xs0), H - 2);
    const int x_hi = min((int)floorf(xs1), H - 2) + 1;
    const int y_lo = min((int)floorf(ys0), H - 2);
    const int y_hi = min((int)floorf(ys1), H - 2) + 1;
    const int WW = x_hi - x_lo + 1;
    const int WH = y_hi - y_lo + 1;
    const int SLOT = WH * WW;              // floats per channel window

    float* __restrict__ outp = out + ((size_t)n * CHANNELS + chunk * CPB) * NPOS;

    if (SLOT <= SLOT_MAX) {
        // ================= staged path =================
        const int q   = tid % NQUAD;       // quad index (pos 4q..4q+3)
        const int sub = tid / NQUAD;       // channel substream 0..4 (5=idle)
        const bool smp = (sub < NSUB);

        // per-position registers: premultiplied weights + slot offset
        float w00[4], w01[4], w10[4], w11[4];
        int   a0[4];
        #pragma unroll
        for (int j = 0; j < 4; ++j) {
            const int p  = 4 * q + j;
            const int py = p / CROP;
            const int px = p - py * CROP;

            const float gy  = (float)py / 13.0f;
            const float ysv = ys0 + (ys1 - ys0) * gy;
            const float yfv = floorf(ysv);
            const float ly  = ysv - yfv;                  // unclamped (ref)
            const int   yi0 = min((int)yfv, H - 1);       // ysv >= 0
            const bool  ycl = (yi0 == H - 1);
            const int   byl = (ycl ? H - 2 : yi0) - y_lo;
            const float wy0 = ycl ? 0.0f : 1.0f - ly;
            const float wy1 = ycl ? 1.0f : ly;

            const float gx  = (float)px / 13.0f;
            const float xsv = xs0 + (xs1 - xs0) * gx;
            const float xfv = floorf(xsv);
            const float lx  = xsv - xfv;
            const int   xi0 = min((int)xfv, H - 1);
            const bool  xcl = (xi0 == H - 1);
            const int   bxl = (xcl ? H - 2 : xi0) - x_lo;
            const float wx0 = xcl ? 0.0f : 1.0f - lx;
            const float wx1 = xcl ? 1.0f : lx;

            a0[j]  = byl * WW + bxl;
            w00[j] = wy0 * wx0;           // ref weight products
            w01[j] = wy0 * wx1;
            w10[j] = wy1 * wx0;
            w11[j] = wy1 * wx1;
        }
        float* __restrict__ opq = outp + 4 * q;   // quad base in channel row

        int CG = LDS_HALF / SLOT; if (CG > CPB) CG = CPB;

        // staging lane geometry: lane-linear LDS dest (global_load_lds contract)
        const int  wyo  = lane / WW;
        const int  wxl  = lane - wyo * WW;
        const int  kR   = 64 / WW;           // full rows per pass
        const int  kRWW = kR * WW;
        const bool wok  = (lane < kRWW);

        auto stage = [&](int g0, int gn, int buf) {
            for (int c = wid; c < gn; c += 4) {
                const float* __restrict__ f = base + (size_t)(g0 + c) * HW
                                                   + (size_t)y_lo * H + x_lo;
                for (int p = 0; p * kR < WH; ++p) {
                    const int row = p * kR + wyo;
                    if (wok && row < WH) {
                        __builtin_amdgcn_global_load_lds(
                            (const __attribute__((address_space(1))) void*)(f + row * H + wxl),
                            (__attribute__((address_space(3))) void*)&win[buf][c * SLOT + p * kRWW],
                            4, 0, 0);
                    }
                }
            }
        };

        stage(0, min(CG, CPB), 0);

        int gi = 0;
        for (int g0 = 0; g0 < CPB; g0 += CG, ++gi) {
            const int gn = min(CG, CPB - g0);
            // vmcnt(0)+barrier: current buffer arrived; prev sampling done.
            __syncthreads();

            const int nx = g0 + CG;
            if (nx < CPB) stage(nx, min(CG, CPB - nx), (gi + 1) & 1);

            if (smp) {
                const float* __restrict__ w = win[gi & 1];
                for (int c = sub; c < gn; c += NSUB) {
                    const int sb = c * SLOT;
                    fx4 r;
                    #pragma unroll
                    for (int j = 0; j < 4; ++j) {
                        const int a = sb + a0[j];
                        const float v00 = w[a];
                        const float v01 = w[a + 1];       // ds_read2 pair
                        const float v10 = w[a + WW];
                        const float v11 = w[a + WW + 1];  // ds_read2 pair
                        r[j] = v00 * w00[j] + v01 * w01[j]
                             + v10 * w10[j] + v11 * w11[j];
                    }
                    *reinterpret_cast<fx4*>(opq + (size_t)(g0 + c) * NPOS) = r;
                }
            }
        }
    } else {
        // ================= direct fallback (safety; not expected) ==========
        if (tid < NPOS) {
            const int pos = tid;
            const int py  = pos / CROP;
            const int px  = pos - py * CROP;

            const float gy  = (float)py / 13.0f;
            const float ysv = ys0 + (ys1 - ys0) * gy;
            const float yfv = floorf(ysv);
            const float ly  = ysv - yfv;
            const int   yi0 = min((int)yfv, H - 1);
            const float gx  = (float)px / 13.0f;
            const float xsv = xs0 + (xs1 - xs0) * gx;
            const float xfv = floorf(xsv);
            const float lx  = xsv - xfv;
            const int   xi0 = min((int)xfv, H - 1);

            const int yi1 = min(yi0 + 1, H - 1);
            const int xi1 = min(xi0 + 1, H - 1);
            const int o00 = yi0 * H + xi0;
            const int o01 = yi0 * H + xi1;
            const int o10 = yi1 * H + xi0;
            const int o11 = yi1 * H + xi1;
            const float omy = 1.0f - ly, omx = 1.0f - lx;
            const float w00 = omy * omx, w01 = omy * lx;
            const float w10 = ly * omx,  w11 = ly * lx;

            #pragma unroll 4
            for (int c = 0; c < CPB; ++c) {
                const float* __restrict__ f = base + (size_t)c * HW;
                const float v = f[o00] * w00 + f[o01] * w01
                              + f[o10] * w10 + f[o11] * w11;
                outp[(size_t)c * NPOS + pos] = v;
            }
        }
    }
}

extern "C" void kernel_launch(void* const* d_in, const int* in_sizes, int n_in,
                              void* d_out, int out_size, void* d_ws, size_t ws_size,
                              hipStream_t stream) {
    const float* p2    = (const float*)d_in[0];
    const float* p3    = (const float*)d_in[1];
    const float* p4    = (const float*)d_in[2];
    const float* p5    = (const float*)d_in[3];
    const float* props = (const float*)d_in[4];
    float* outp        = (float*)d_out;

    const int N = in_sizes[4] / 7;          // 1024 proposals
    dim3 grid(N * 4);                       // 4096 blocks
    dim3 block(256);
    hipLaunchKernelGGL(crop_roi_kernel, grid, block, 0, stream,
                       p2, p3, p4, p5, props, outp);
}

// Round 13
// 62.694 us; speedup vs baseline: 1.7521x; 1.0928x over previous
//
#include <hip/hip_runtime.h>

#define CROP 14
#define NPOS (CROP * CROP)       // 196
#define CHANNELS 256
#define CPB 16                   // channels per block (16 blocks per proposal)
#define NBLK (CHANNELS / CPB)    // 16
#define LDS_FLOATS 4096          // 16 KiB -> holds 16 windows for SLOT<=256
#define SLOT_MAX 392             // fallback threshold (safety; SLOT<=~350 by geometry)
#define NQUAD 49                 // 4-position quads per channel
#define NSUB 5                   // channel substreams (5*49=245 active threads)

typedef float __attribute__((ext_vector_type(4))) fx4;

// Block = (proposal, 16-channel slice). Stage all 16 ROI windows via async
// global_load_lds, ONE __syncthreads drain, sample quads + dwordx4 stores.
// Overlap comes from 8 resident blocks/CU at staggered phases (TLP), not
// from intra-block pipelining.
__global__ __launch_bounds__(256) void crop_roi_kernel(
    const float* __restrict__ p2, const float* __restrict__ p3,
    const float* __restrict__ p4, const float* __restrict__ p5,
    const float* __restrict__ props, float* __restrict__ out)
{
    const int blk   = blockIdx.x;
    const int n     = blk >> 4;            // proposal
    const int chunk = blk & 15;            // 16-channel slice
    const int tid   = threadIdx.x;
    const int lane  = tid & 63;
    const int wid   = tid >> 6;

    __shared__ float win[LDS_FLOATS];

    // ---- proposal setup (uniform across block; computed redundantly) ----
    const int   bimg = (int)props[n * 7 + 0];
    const float bx0  = props[n * 7 + 1];
    const float by0  = props[n * 7 + 2];
    const float bx1  = props[n * 7 + 3];
    const float by1  = props[n * 7 + 4];

    const float sz = sqrtf((bx1 - bx0) * (by1 - by0));
    int lvl = 0; float bd = fabsf(sz - 8.0f), d;
    d = fabsf(sz - 16.0f); if (d < bd) { bd = d; lvl = 1; }
    d = fabsf(sz - 32.0f); if (d < bd) { bd = d; lvl = 2; }
    d = fabsf(sz - 64.0f); if (d < bd) { bd = d; lvl = 3; }

    const int   H     = 256 >> lvl;                 // H == W
    const int   HW    = H * H;
    const float scale = 0.25f / (float)(1 << lvl);  // exact
    const float* fp   = (lvl == 0) ? p2 : (lvl == 1) ? p3 : (lvl == 2) ? p4 : p5;
    const float* base = fp + (size_t)bimg * CHANNELS * HW
                           + (size_t)(chunk * CPB) * HW;

    // ---- window bounds (uniform) ----
    const float xs0 = bx0 * scale, xs1 = bx1 * scale;
    const float ys0 = by0 * scale, ys1 = by1 * scale;
    const int x_lo = min((int)floorf(xs0), H - 2);
    const int x_hi = min((int)floorf(xs1), H - 2) + 1;
    const int y_lo = min((int)floorf(ys0), H - 2);
    const int y_hi = min((int)floorf(ys1), H - 2) + 1;
    const int WW = x_hi - x_lo + 1;
    const int WH = y_hi - y_lo + 1;
    const int SLOT = WH * WW;              // floats per channel window

    float* __restrict__ outp = out + ((size_t)n * CHANNELS + chunk * CPB) * NPOS;

    if (SLOT <= SLOT_MAX) {
        // ================= staged path =================
        const int q   = tid % NQUAD;       // quad index (pos 4q..4q+3)
        const int sub = tid / NQUAD;       // channel substream 0..4 (5=idle)
        const bool smp = (sub < NSUB);

        // per-position registers: premultiplied weights + slot offset
        float w00[4], w01[4], w10[4], w11[4];
        int   a0[4];
        #pragma unroll
        for (int j = 0; j < 4; ++j) {
            const int p  = 4 * q + j;
            const int py = p / CROP;
            const int px = p - py * CROP;

            const float gy  = (float)py / 13.0f;
            const float ysv = ys0 + (ys1 - ys0) * gy;
            const float yfv = floorf(ysv);
            const float ly  = ysv - yfv;                  // unclamped (ref)
            const int   yi0 = min((int)yfv, H - 1);       // ysv >= 0
            const bool  ycl = (yi0 == H - 1);
            const int   byl = (ycl ? H - 2 : yi0) - y_lo;
            const float wy0 = ycl ? 0.0f : 1.0f - ly;
            const float wy1 = ycl ? 1.0f : ly;

            const float gx  = (float)px / 13.0f;
            const float xsv = xs0 + (xs1 - xs0) * gx;
            const float xfv = floorf(xsv);
            const float lx  = xsv - xfv;
            const int   xi0 = min((int)xfv, H - 1);
            const bool  xcl = (xi0 == H - 1);
            const int   bxl = (xcl ? H - 2 : xi0) - x_lo;
            const float wx0 = xcl ? 0.0f : 1.0f - lx;
            const float wx1 = xcl ? 1.0f : lx;

            a0[j]  = byl * WW + bxl;
            w00[j] = wy0 * wx0;
            w01[j] = wy0 * wx1;
            w10[j] = wy1 * wx0;
            w11[j] = wy1 * wx1;
        }
        float* __restrict__ opq = outp + 4 * q;

        int CG = LDS_FLOATS / SLOT; if (CG > CPB) CG = CPB;  // >= 10 always

        // staging lane geometry: lane-linear LDS dest (global_load_lds contract)
        const int  wyo  = lane / WW;
        const int  wxl  = lane - wyo * WW;
        const int  kR   = 64 / WW;           // full rows per pass (>=2)
        const int  kRWW = kR * WW;
        const bool wok  = (lane < kRWW);

        // groups: 1 for SLOT<=256 (~95% of blocks), 2 for the big-window tail
        for (int g0 = 0; g0 < CPB; g0 += CG) {
            const int gn = min(CG, CPB - g0);
            if (g0) __syncthreads();       // rare 2nd group: protect reads

            // stage: wave w handles channels w, w+4, ... (async -> LDS)
            for (int c = wid; c < gn; c += 4) {
                const float* __restrict__ f = base + (size_t)(g0 + c) * HW
                                                   + (size_t)y_lo * H + x_lo;
                for (int p = 0; p * kR < WH; ++p) {
                    const int row = p * kR + wyo;
                    if (wok && row < WH) {
                        __builtin_amdgcn_global_load_lds(
                            (const __attribute__((address_space(1))) void*)(f + row * H + wxl),
                            (__attribute__((address_space(3))) void*)&win[c * SLOT + p * kRWW],
                            4, 0, 0);
                    }
                }
            }
            __syncthreads();               // vmcnt(0) drain: windows resident

            if (smp) {
                for (int c = sub; c < gn; c += NSUB) {
                    const int sb = c * SLOT;
                    fx4 r;
                    #pragma unroll
                    for (int j = 0; j < 4; ++j) {
                        const int a = sb + a0[j];
                        const float v00 = win[a];
                        const float v01 = win[a + 1];       // ds_read2 pair
                        const float v10 = win[a + WW];
                        const float v11 = win[a + WW + 1];  // ds_read2 pair
                        r[j] = v00 * w00[j] + v01 * w01[j]
                             + v10 * w10[j] + v11 * w11[j];
                    }
                    *reinterpret_cast<fx4*>(opq + (size_t)(g0 + c) * NPOS) = r;
                }
            }
        }
    } else {
        // ================= direct fallback (safety; not expected) ==========
        if (tid < NPOS) {
            const int pos = tid;
            const int py  = pos / CROP;
            const int px  = pos - py * CROP;

            const float gy  = (float)py / 13.0f;
            const float ysv = ys0 + (ys1 - ys0) * gy;
            const float yfv = floorf(ysv);
            const float ly  = ysv - yfv;
            const int   yi0 = min((int)yfv, H - 1);
            const float gx  = (float)px / 13.0f;
            const float xsv = xs0 + (xs1 - xs0) * gx;
            const float xfv = floorf(xsv);
            const float lx  = xsv - xfv;
            const int   xi0 = min((int)xfv, H - 1);

            const int yi1 = min(yi0 + 1, H - 1);
            const int xi1 = min(xi0 + 1, H - 1);
            const int o00 = yi0 * H + xi0;
            const int o01 = yi0 * H + xi1;
            const int o10 = yi1 * H + xi0;
            const int o11 = yi1 * H + xi1;
            const float omy = 1.0f - ly, omx = 1.0f - lx;
            const float w00 = omy * omx, w01 = omy * lx;
            const float w10 = ly * omx,  w11 = ly * lx;

            #pragma unroll 4
            for (int c = 0; c < CPB; ++c) {
                const float* __restrict__ f = base + (size_t)c * HW;
                const float v = f[o00] * w00 + f[o01] * w01
                              + f[o10] * w10 + f[o11] * w11;
                outp[(size_t)c * NPOS + pos] = v;
            }
        }
    }
}

extern "C" void kernel_launch(void* const* d_in, const int* in_sizes, int n_in,
                              void* d_out, int out_size, void* d_ws, size_t ws_size,
                              hipStream_t stream) {
    const float* p2    = (const float*)d_in[0];
    const float* p3    = (const float*)d_in[1];
    const float* p4    = (const float*)d_in[2];
    const float* p5    = (const float*)d_in[3];
    const float* props = (const float*)d_in[4];
    float* outp        = (float*)d_out;

    const int N = in_sizes[4] / 7;          // 1024 proposals
    dim3 grid(N * NBLK);                    // 16384 blocks
    dim3 block(256);
    hipLaunchKernelGGL(crop_roi_kernel, grid, block, 0, stream,
                       p2, p3, p4, p5, props, outp);
}